// Round 10
// baseline (145.433 us; speedup 1.0000x reference)
//
#include <hip/hip_runtime.h>

#define NN 50000
#define NE 800000
#define NG 64
#define HID 64
#define NEG 0.2f
#define NPW 64          // nodes per wave in k_node
#define NBUCK 196       // ceil(NN/256) coarse buckets (dst>>8)
#define CHUNK 2048      // edges per k_bucket block
#define KC_CAP 6144     // per-bucket ebuf segment (mean 4096 + 32 sigma)

// ---------------- K1: h = x @ W ; a_s = h.att_src ; a_d = h.att_dst --------
// Register-tiled f32 GEMM: block = 16x16 threads, 64-row tile, 4x4 micro-tile.
// Block 0 also zeroes gcur for the downstream k_bucket (runs after k_xw).
__global__ __launch_bounds__(256)
void k_xw(const float* __restrict__ x, const float* __restrict__ W,
          const float* __restrict__ att_s, const float* __restrict__ att_d,
          float* __restrict__ h, float* __restrict__ as_, float* __restrict__ ad_,
          int* __restrict__ gcur) {
    __shared__ __align__(16) float sW[64][64];    // [k][c]
    __shared__ __align__(16) float sxT[64][68];   // [k][r]
    int t = threadIdx.x;
    if (blockIdx.x == 0 && t < NBUCK) gcur[t] = 0;   // replaces hipMemsetAsync
    int r0 = blockIdx.x * 64;
    for (int i = t; i < 4096; i += 256) sW[i >> 6][i & 63] = W[i];
    for (int i = t; i < 4096; i += 256) {
        int r = i >> 6, c = i & 63;
        int gr = r0 + r; if (gr >= NN) gr = NN - 1;
        sxT[c][r] = x[(size_t)gr * 64 + c];
    }
    __syncthreads();

    int tx = t & 15, ty = t >> 4;
    float4 asv = ((const float4*)att_s)[tx];
    float4 adv = ((const float4*)att_d)[tx];

    float acc[4][4] = {};
    #pragma unroll
    for (int k = 0; k < 64; ++k) {
        float4 a = *(const float4*)&sxT[k][4 * ty];
        float4 b = *(const float4*)&sW[k][4 * tx];
        float av[4] = {a.x, a.y, a.z, a.w};
        float bv[4] = {b.x, b.y, b.z, b.w};
        #pragma unroll
        for (int i = 0; i < 4; ++i)
            #pragma unroll
            for (int j = 0; j < 4; ++j)
                acc[i][j] += av[i] * bv[j];
    }

    #pragma unroll
    for (int i = 0; i < 4; ++i) {
        int r = r0 + 4 * ty + i;
        if (r < NN) {
            float4 hv = make_float4(acc[i][0], acc[i][1], acc[i][2], acc[i][3]);
            *(float4*)&h[(size_t)r * 64 + 4 * tx] = hv;
            float ps = acc[i][0]*asv.x + acc[i][1]*asv.y + acc[i][2]*asv.z + acc[i][3]*asv.w;
            float pd = acc[i][0]*adv.x + acc[i][1]*adv.y + acc[i][2]*adv.z + acc[i][3]*adv.w;
            #pragma unroll
            for (int m = 1; m <= 8; m <<= 1) {
                ps += __shfl_xor(ps, m, 64);
                pd += __shfl_xor(pd, m, 64);
            }
            if (tx == 0) { as_[r] = ps; ad_[r] = pd; }
        }
    }
}

// ---------------- Pass B: blockwise bucket sort (dst>>8) ------------------
__global__ __launch_bounds__(256)
void k_bucket(const int* __restrict__ src, const int* __restrict__ dst,
              int* __restrict__ gcur, int* __restrict__ ebuf) {
    __shared__ int lhist[256], lscan[256], loff[256], lcur[256], gbase[256];
    __shared__ int lsort[CHUNK];
    __shared__ unsigned char lbuck[CHUNK];
    int t = threadIdx.x;
    int base = blockIdx.x * CHUNK;
    int cnt = NE - base; if (cnt > CHUNK) cnt = CHUNK; if (cnt < 0) cnt = 0;

    int ds[8], ss[8];
    int nv = 0;
    #pragma unroll
    for (int j = 0; j < 8; ++j) {
        int e = base + j * 256 + t;
        if (e < NE) { ds[nv] = dst[e]; ss[nv] = src[e]; ++nv; }
    }
    lhist[t] = 0;
    __syncthreads();
    for (int j = 0; j < nv; ++j) atomicAdd(&lhist[ds[j] >> 8], 1);
    __syncthreads();
    lscan[t] = lhist[t];
    __syncthreads();
    for (int off = 1; off < 256; off <<= 1) {
        int u = (t >= off) ? lscan[t - off] : 0;
        __syncthreads();
        lscan[t] += u;
        __syncthreads();
    }
    loff[t] = lscan[t] - lhist[t];   // exclusive
    lcur[t] = 0;
    __syncthreads();
    for (int j = 0; j < nv; ++j) {
        int b = ds[j] >> 8;
        int r = atomicAdd(&lcur[b], 1);
        int slot = loff[b] + r;
        lsort[slot] = (ss[j] << 8) | (ds[j] & 255);   // src<50000 fits in 24b
        lbuck[slot] = (unsigned char)b;
    }
    if (t < NBUCK) {
        int c = lhist[t];
        gbase[t] = c ? atomicAdd(&gcur[t], c) : 0;    // offset WITHIN bucket t
    }
    __syncthreads();
    for (int i = t; i < cnt; i += 256) {
        int b = lbuck[i];
        ebuf[b * KC_CAP + gbase[b] + (i - loff[b])] = lsort[i];
    }
}

// ---------------- Pass C: exact CSR within each bucket --------------------
__global__ __launch_bounds__(256)
void k_csr(const int* __restrict__ gcur, const int* __restrict__ ebuf,
           int* __restrict__ csr, int* __restrict__ cursor, int* __restrict__ deg) {
    __shared__ int lhist[256], lscan[256], loff[256], lcur[256], bscan[256];
    __shared__ int lsrc[KC_CAP];
    int t = threadIdx.x;
    int b = blockIdx.x;

    bscan[t] = (t < NBUCK) ? gcur[t] : 0;     // bucket sizes
    __syncthreads();
    for (int off = 1; off < 256; off <<= 1) {
        int u = (t >= off) ? bscan[t - off] : 0;
        __syncthreads();
        bscan[t] += u;
        __syncthreads();
    }
    int sz = gcur[b];                          // this bucket's edge count
    int gb = bscan[b] - sz;                    // dense CSR base (exclusive)
    const int* seg = ebuf + b * KC_CAP;

    lhist[t] = 0;
    __syncthreads();
    for (int i = t; i < sz; i += 256)
        atomicAdd(&lhist[seg[i] & 255], 1);
    __syncthreads();
    lscan[t] = lhist[t];
    __syncthreads();
    for (int off = 1; off < 256; off <<= 1) {
        int u = (t >= off) ? lscan[t - off] : 0;
        __syncthreads();
        lscan[t] += u;
        __syncthreads();
    }
    loff[t] = lscan[t] - lhist[t];
    lcur[t] = 0;
    __syncthreads();
    for (int i = t; i < sz; i += 256) {
        int w = seg[i];
        int dl = w & 255;
        int r = atomicAdd(&lcur[dl], 1);
        lsrc[loff[dl] + r] = w >> 8;
    }
    __syncthreads();
    for (int i = t; i < sz; i += 256)
        csr[gb + i] = lsrc[i];
    int d = b * 256 + t;
    if (d < NN) {
        deg[d] = lhist[t];
        cursor[d] = gb + loff[t] + lhist[t];   // end offset
    }
}

// ---------------- K2': gather per dst node, 16-ahead prefetch -------------
// Lanes cooperatively load 16 csr indices + as_ values in one coalesced
// fetch, broadcast via shfl(width 16); inner loop issues h-row loads
// back-to-back (addresses known 16 ahead) -> deep MLP pipeline.
__global__ __launch_bounds__(256)
void k_gather(const int* __restrict__ csr, const int* __restrict__ cursor,
              const int* __restrict__ deg, const float* __restrict__ h,
              const float* __restrict__ as_, const float* __restrict__ ad_,
              const float* __restrict__ bias, float* __restrict__ g,
              float* __restrict__ poolz) {
    int t = threadIdx.x;
    if (blockIdx.x == 0) {                        // replaces hipMemsetAsync
        for (int i = t; i < NG * HID + NG; i += 256) poolz[i] = 0.f;
    }
    int wave = t >> 6, lane = t & 63;
    int d = blockIdx.x * 4 + wave;
    if (d >= NN) return;
    int cend = cursor[d];
    int nd   = deg[d];
    int cbeg = cend - nd;
    float adv = ad_[d];
    float e0 = as_[d] + adv;
    e0 = e0 >= 0.f ? e0 : NEG * e0;
    float ex0 = __expf(e0);
    float den = ex0;
    float acc = h[(size_t)d * 64 + lane] * ex0;

    for (int c0 = 0; c0 < nd; c0 += 16) {
        int rem = nd - c0; if (rem > 16) rem = 16;
        int ci = cbeg + c0 + (lane & 15);
        if (ci >= cend) ci = cend - 1;             // clamp (tail lanes unused)
        int   myidx = csr[ci];                     // coalesced 64B (x4 bcast)
        float myas  = as_[myidx];                  // prefetched alongside
        if (rem == 16) {
            #pragma unroll
            for (int j = 0; j < 16; ++j) {
                int   s = __shfl(myidx, j, 16);
                float a = __shfl(myas,  j, 16);
                float av = a + adv;
                av = av >= 0.f ? av : NEG * av;
                float ex = __expf(av);
                den += ex;
                acc += h[(size_t)s * 64 + lane] * ex;
            }
        } else {
            for (int j = 0; j < rem; ++j) {
                int   s = __shfl(myidx, j, 16);
                float a = __shfl(myas,  j, 16);
                float av = a + adv;
                av = av >= 0.f ? av : NEG * av;
                float ex = __expf(av);
                den += ex;
                acc += h[(size_t)s * 64 + lane] * ex;
            }
        }
    }
    g[(size_t)d * 64 + lane] = fmaxf(acc / den + bias[lane], 0.f);
}

// ---------------- K3: pooled partial sums (batch sorted, run-length) ------
__global__ __launch_bounds__(256)
void k_node(const float* __restrict__ g, const int* __restrict__ batch,
            float* __restrict__ pooled, float* __restrict__ cnt) {
    int t = threadIdx.x;
    int wave = t >> 6, lane = t & 63;
    int n0 = (blockIdx.x * 4 + wave) * NPW;
    if (n0 >= NN) return;
    int n1 = n0 + NPW; if (n1 > NN) n1 = NN;
    float acc = 0.f, c = 0.f;
    int cur = batch[n0];
    for (int n = n0; n < n1; ++n) {
        int gr = batch[n];
        if (gr != cur) {
            atomicAdd(&pooled[cur * 64 + lane], acc);
            if (lane == 0) atomicAdd(&cnt[cur], c);
            acc = 0.f; c = 0.f; cur = gr;
        }
        acc += g[(size_t)n * 64 + lane];
        c += 1.f;
    }
    atomicAdd(&pooled[cur * 64 + lane], acc);
    if (lane == 0) atomicAdd(&cnt[cur], c);
}

// ---------------- K4: mean + MLP + sigmoid (single block) ------------------
__global__ __launch_bounds__(256)
void k_final(const float* __restrict__ pooled, const float* __restrict__ cnt,
             const float* __restrict__ w1, const float* __restrict__ b1,
             const float* __restrict__ w2, const float* __restrict__ b2,
             float* __restrict__ out) {
    __shared__ float sp[64][65];
    __shared__ float sz[64][65];
    int t = threadIdx.x;
    for (int i = t; i < 4096; i += 256) {
        int g = i >> 6, c = i & 63;
        sp[g][c] = pooled[i] / fmaxf(cnt[g], 1.0f);
    }
    __syncthreads();
    for (int i = t; i < 4096; i += 256) {
        int g = i >> 6, c = i & 63;
        float acc = b1[c];
        #pragma unroll
        for (int k = 0; k < 64; ++k) acc += sp[g][k] * w1[k * 64 + c];
        sz[g][c] = fmaxf(acc, 0.f);
    }
    __syncthreads();
    if (t < 64) {
        float acc = b2[0];
        #pragma unroll
        for (int c = 0; c < 64; ++c) acc += sz[t][c] * w2[c];
        out[t] = 1.f / (1.f + __expf(-acc));
    }
}

extern "C" void kernel_launch(void* const* d_in, const int* in_sizes, int n_in,
                              void* d_out, int out_size, void* d_ws, size_t ws_size,
                              hipStream_t stream) {
    const float* x     = (const float*)d_in[0];
    const int*   ei    = (const int*)d_in[1];   // [2, NE] flat: src row then dst row
    const int*   batch = (const int*)d_in[2];
    const float* W     = (const float*)d_in[3];
    const float* att_s = (const float*)d_in[4];
    const float* att_d = (const float*)d_in[5];
    const float* bias  = (const float*)d_in[6];
    const float* w1    = (const float*)d_in[7];
    const float* b1    = (const float*)d_in[8];
    const float* w2    = (const float*)d_in[9];
    const float* b2    = (const float*)d_in[10];
    float* out = (float*)d_out;

    const int* src = ei;
    const int* dst = ei + NE;

    // workspace layout (floats / ints)
    float* h      = (float*)d_ws;               // NN*64
    float* as_    = h + (size_t)NN * HID;       // NN
    float* ad_    = as_ + NN;                   // NN
    float* g      = ad_ + NN;                   // NN*64  (ebuf aliases this)
    float* pooled = g + (size_t)NN * HID;       // NG*64
    float* cntp   = pooled + NG * HID;          // NG
    int*   deg    = (int*)(cntp + NG);          // NN
    int*   cursor = deg + NN;                   // NN
    int*   csr    = cursor + NN;                // NE
    int*   gcur   = csr + NE;                   // NBUCK
    int*   ebuf   = (int*)g;                    // NBUCK*KC_CAP (= 4.6MB < NN*64*4)

    k_xw<<<(NN + 63) / 64, 256, 0, stream>>>(x, W, att_s, att_d, h, as_, ad_, gcur);

    k_bucket<<<(NE + CHUNK - 1) / CHUNK, 256, 0, stream>>>(src, dst, gcur, ebuf);
    k_csr<<<NBUCK, 256, 0, stream>>>(gcur, ebuf, csr, cursor, deg);

    k_gather<<<(NN + 3) / 4, 256, 0, stream>>>(csr, cursor, deg, h, as_, ad_, bias, g, pooled);

    k_node<<<(NN / (4 * NPW)) + 1, 256, 0, stream>>>(g, batch, pooled, cntp);

    k_final<<<1, 256, 0, stream>>>(pooled, cntp, w1, b1, w2, b2, out);
}

// Round 11
// 142.677 us; speedup vs baseline: 1.0193x; 1.0193x over previous
//
#include <hip/hip_runtime.h>
#include <hip/hip_bf16.h>

#define NN 50000
#define NE 800000
#define NG 64
#define HID 64
#define NEG 0.2f
#define NPW 64          // nodes per wave in k_node
#define NBUCK 196       // ceil(NN/256) coarse buckets (dst>>8)
#define CHUNK 2048      // edges per k_bucket block
#define KC_CAP 6144     // per-bucket ebuf segment (mean 4096 + 32 sigma)

// bf16 <-> f32 helpers (RNE pack, exact unpack)
__device__ __forceinline__ unsigned short f2bf(float f) {
    unsigned int u = __float_as_uint(f);
    unsigned int r = (u + 0x7FFF + ((u >> 16) & 1)) >> 16;   // round-nearest-even
    return (unsigned short)r;
}
__device__ __forceinline__ float bf2f(unsigned short b) {
    return __uint_as_float(((unsigned int)b) << 16);
}

// ---------------- K1: h(bf16) = x @ W ; a_s ; a_d --------------------------
// Register-tiled f32 GEMM; h stored bf16 (halves gather traffic downstream).
// Block 0 also zeroes gcur for the downstream k_bucket.
__global__ __launch_bounds__(256)
void k_xw(const float* __restrict__ x, const float* __restrict__ W,
          const float* __restrict__ att_s, const float* __restrict__ att_d,
          unsigned short* __restrict__ hb, float* __restrict__ as_, float* __restrict__ ad_,
          int* __restrict__ gcur) {
    __shared__ __align__(16) float sW[64][64];    // [k][c]
    __shared__ __align__(16) float sxT[64][68];   // [k][r]
    int t = threadIdx.x;
    if (blockIdx.x == 0 && t < NBUCK) gcur[t] = 0;
    int r0 = blockIdx.x * 64;
    for (int i = t; i < 4096; i += 256) sW[i >> 6][i & 63] = W[i];
    for (int i = t; i < 4096; i += 256) {
        int r = i >> 6, c = i & 63;
        int gr = r0 + r; if (gr >= NN) gr = NN - 1;
        sxT[c][r] = x[(size_t)gr * 64 + c];
    }
    __syncthreads();

    int tx = t & 15, ty = t >> 4;
    float4 asv = ((const float4*)att_s)[tx];
    float4 adv = ((const float4*)att_d)[tx];

    float acc[4][4] = {};
    #pragma unroll
    for (int k = 0; k < 64; ++k) {
        float4 a = *(const float4*)&sxT[k][4 * ty];
        float4 b = *(const float4*)&sW[k][4 * tx];
        float av[4] = {a.x, a.y, a.z, a.w};
        float bv[4] = {b.x, b.y, b.z, b.w};
        #pragma unroll
        for (int i = 0; i < 4; ++i)
            #pragma unroll
            for (int j = 0; j < 4; ++j)
                acc[i][j] += av[i] * bv[j];
    }

    #pragma unroll
    for (int i = 0; i < 4; ++i) {
        int r = r0 + 4 * ty + i;
        if (r < NN) {
            ushort4 hv;
            hv.x = f2bf(acc[i][0]); hv.y = f2bf(acc[i][1]);
            hv.z = f2bf(acc[i][2]); hv.w = f2bf(acc[i][3]);
            *(ushort4*)&hb[(size_t)r * 64 + 4 * tx] = hv;     // 8B store
            float ps = acc[i][0]*asv.x + acc[i][1]*asv.y + acc[i][2]*asv.z + acc[i][3]*asv.w;
            float pd = acc[i][0]*adv.x + acc[i][1]*adv.y + acc[i][2]*adv.z + acc[i][3]*adv.w;
            #pragma unroll
            for (int m = 1; m <= 8; m <<= 1) {
                ps += __shfl_xor(ps, m, 64);
                pd += __shfl_xor(pd, m, 64);
            }
            if (tx == 0) { as_[r] = ps; ad_[r] = pd; }
        }
    }
}

// ---------------- Pass B: blockwise bucket sort (dst>>8) ------------------
__global__ __launch_bounds__(256)
void k_bucket(const int* __restrict__ src, const int* __restrict__ dst,
              int* __restrict__ gcur, int* __restrict__ ebuf) {
    __shared__ int lhist[256], lscan[256], loff[256], lcur[256], gbase[256];
    __shared__ int lsort[CHUNK];
    __shared__ unsigned char lbuck[CHUNK];
    int t = threadIdx.x;
    int base = blockIdx.x * CHUNK;
    int cnt = NE - base; if (cnt > CHUNK) cnt = CHUNK; if (cnt < 0) cnt = 0;

    int ds[8], ss[8];
    int nv = 0;
    #pragma unroll
    for (int j = 0; j < 8; ++j) {
        int e = base + j * 256 + t;
        if (e < NE) { ds[nv] = dst[e]; ss[nv] = src[e]; ++nv; }
    }
    lhist[t] = 0;
    __syncthreads();
    for (int j = 0; j < nv; ++j) atomicAdd(&lhist[ds[j] >> 8], 1);
    __syncthreads();
    lscan[t] = lhist[t];
    __syncthreads();
    for (int off = 1; off < 256; off <<= 1) {
        int u = (t >= off) ? lscan[t - off] : 0;
        __syncthreads();
        lscan[t] += u;
        __syncthreads();
    }
    loff[t] = lscan[t] - lhist[t];   // exclusive
    lcur[t] = 0;
    __syncthreads();
    for (int j = 0; j < nv; ++j) {
        int b = ds[j] >> 8;
        int r = atomicAdd(&lcur[b], 1);
        int slot = loff[b] + r;
        lsort[slot] = (ss[j] << 8) | (ds[j] & 255);   // src<50000 fits in 24b
        lbuck[slot] = (unsigned char)b;
    }
    if (t < NBUCK) {
        int c = lhist[t];
        gbase[t] = c ? atomicAdd(&gcur[t], c) : 0;    // offset WITHIN bucket t
    }
    __syncthreads();
    for (int i = t; i < cnt; i += 256) {
        int b = lbuck[i];
        ebuf[b * KC_CAP + gbase[b] + (i - loff[b])] = lsort[i];
    }
}

// ---------------- Pass C: exact CSR within each bucket --------------------
__global__ __launch_bounds__(256)
void k_csr(const int* __restrict__ gcur, const int* __restrict__ ebuf,
           int* __restrict__ csr, int* __restrict__ cursor, int* __restrict__ deg) {
    __shared__ int lhist[256], lscan[256], loff[256], lcur[256], bscan[256];
    __shared__ int lsrc[KC_CAP];
    int t = threadIdx.x;
    int b = blockIdx.x;

    bscan[t] = (t < NBUCK) ? gcur[t] : 0;     // bucket sizes
    __syncthreads();
    for (int off = 1; off < 256; off <<= 1) {
        int u = (t >= off) ? bscan[t - off] : 0;
        __syncthreads();
        bscan[t] += u;
        __syncthreads();
    }
    int sz = gcur[b];                          // this bucket's edge count
    int gb = bscan[b] - sz;                    // dense CSR base (exclusive)
    const int* seg = ebuf + b * KC_CAP;

    lhist[t] = 0;
    __syncthreads();
    for (int i = t; i < sz; i += 256)
        atomicAdd(&lhist[seg[i] & 255], 1);
    __syncthreads();
    lscan[t] = lhist[t];
    __syncthreads();
    for (int off = 1; off < 256; off <<= 1) {
        int u = (t >= off) ? lscan[t - off] : 0;
        __syncthreads();
        lscan[t] += u;
        __syncthreads();
    }
    loff[t] = lscan[t] - lhist[t];
    lcur[t] = 0;
    __syncthreads();
    for (int i = t; i < sz; i += 256) {
        int w = seg[i];
        int dl = w & 255;
        int r = atomicAdd(&lcur[dl], 1);
        lsrc[loff[dl] + r] = w >> 8;
    }
    __syncthreads();
    for (int i = t; i < sz; i += 256)
        csr[gb + i] = lsrc[i];
    int d = b * 256 + t;
    if (d < NN) {
        deg[d] = lhist[t];
        cursor[d] = gb + loff[t] + lhist[t];   // end offset
    }
}

// ---------------- K2': gather per dst node (bf16 h rows) ------------------
__global__ __launch_bounds__(256)
void k_gather(const int* __restrict__ csr, const int* __restrict__ cursor,
              const int* __restrict__ deg, const unsigned short* __restrict__ hb,
              const float* __restrict__ as_, const float* __restrict__ ad_,
              const float* __restrict__ bias, float* __restrict__ g,
              float* __restrict__ poolz) {
    int t = threadIdx.x;
    if (blockIdx.x == 0) {                        // replaces hipMemsetAsync
        for (int i = t; i < NG * HID + NG; i += 256) poolz[i] = 0.f;
    }
    int wave = t >> 6, lane = t & 63;
    int d = blockIdx.x * 4 + wave;
    if (d >= NN) return;
    int cend = cursor[d];
    int nd   = deg[d];
    int cbeg = cend - nd;
    float adv = ad_[d];
    float e0 = as_[d] + adv;
    e0 = e0 >= 0.f ? e0 : NEG * e0;
    float ex0 = __expf(e0);
    float den = ex0;
    float acc = bf2f(hb[(size_t)d * 64 + lane]) * ex0;

    for (int c0 = 0; c0 < nd; c0 += 16) {
        int rem = nd - c0; if (rem > 16) rem = 16;
        int ci = cbeg + c0 + (lane & 15);
        if (ci >= cend) ci = cend - 1;             // clamp (tail lanes unused)
        int   myidx = csr[ci];                     // coalesced 64B (x4 bcast)
        float myas  = as_[myidx];                  // prefetched alongside
        if (rem == 16) {
            #pragma unroll
            for (int j = 0; j < 16; ++j) {
                int   s = __shfl(myidx, j, 16);
                float a = __shfl(myas,  j, 16);
                float av = a + adv;
                av = av >= 0.f ? av : NEG * av;
                float ex = __expf(av);
                den += ex;
                acc += bf2f(hb[(size_t)s * 64 + lane]) * ex;  // 128B/wave
            }
        } else {
            for (int j = 0; j < rem; ++j) {
                int   s = __shfl(myidx, j, 16);
                float a = __shfl(myas,  j, 16);
                float av = a + adv;
                av = av >= 0.f ? av : NEG * av;
                float ex = __expf(av);
                den += ex;
                acc += bf2f(hb[(size_t)s * 64 + lane]) * ex;
            }
        }
    }
    g[(size_t)d * 64 + lane] = fmaxf(acc / den + bias[lane], 0.f);
}

// ---------------- K3: pooled partial sums (batch sorted, run-length) ------
__global__ __launch_bounds__(256)
void k_node(const float* __restrict__ g, const int* __restrict__ batch,
            float* __restrict__ pooled, float* __restrict__ cnt) {
    int t = threadIdx.x;
    int wave = t >> 6, lane = t & 63;
    int n0 = (blockIdx.x * 4 + wave) * NPW;
    if (n0 >= NN) return;
    int n1 = n0 + NPW; if (n1 > NN) n1 = NN;
    float acc = 0.f, c = 0.f;
    int cur = batch[n0];
    for (int n = n0; n < n1; ++n) {
        int gr = batch[n];
        if (gr != cur) {
            atomicAdd(&pooled[cur * 64 + lane], acc);
            if (lane == 0) atomicAdd(&cnt[cur], c);
            acc = 0.f; c = 0.f; cur = gr;
        }
        acc += g[(size_t)n * 64 + lane];
        c += 1.f;
    }
    atomicAdd(&pooled[cur * 64 + lane], acc);
    if (lane == 0) atomicAdd(&cnt[cur], c);
}

// ---------------- K4: mean + MLP + sigmoid (single block) ------------------
__global__ __launch_bounds__(256)
void k_final(const float* __restrict__ pooled, const float* __restrict__ cnt,
             const float* __restrict__ w1, const float* __restrict__ b1,
             const float* __restrict__ w2, const float* __restrict__ b2,
             float* __restrict__ out) {
    __shared__ float sp[64][65];
    __shared__ float sz[64][65];
    int t = threadIdx.x;
    for (int i = t; i < 4096; i += 256) {
        int g = i >> 6, c = i & 63;
        sp[g][c] = pooled[i] / fmaxf(cnt[g], 1.0f);
    }
    __syncthreads();
    for (int i = t; i < 4096; i += 256) {
        int g = i >> 6, c = i & 63;
        float acc = b1[c];
        #pragma unroll
        for (int k = 0; k < 64; ++k) acc += sp[g][k] * w1[k * 64 + c];
        sz[g][c] = fmaxf(acc, 0.f);
    }
    __syncthreads();
    if (t < 64) {
        float acc = b2[0];
        #pragma unroll
        for (int c = 0; c < 64; ++c) acc += sz[t][c] * w2[c];
        out[t] = 1.f / (1.f + __expf(-acc));
    }
}

extern "C" void kernel_launch(void* const* d_in, const int* in_sizes, int n_in,
                              void* d_out, int out_size, void* d_ws, size_t ws_size,
                              hipStream_t stream) {
    const float* x     = (const float*)d_in[0];
    const int*   ei    = (const int*)d_in[1];   // [2, NE] flat: src row then dst row
    const int*   batch = (const int*)d_in[2];
    const float* W     = (const float*)d_in[3];
    const float* att_s = (const float*)d_in[4];
    const float* att_d = (const float*)d_in[5];
    const float* bias  = (const float*)d_in[6];
    const float* w1    = (const float*)d_in[7];
    const float* b1    = (const float*)d_in[8];
    const float* w2    = (const float*)d_in[9];
    const float* b2    = (const float*)d_in[10];
    float* out = (float*)d_out;

    const int* src = ei;
    const int* dst = ei + NE;

    // workspace layout
    unsigned short* hb = (unsigned short*)d_ws;     // NN*64 bf16 (1.6M shorts)
    float* as_    = (float*)(hb + (size_t)NN * HID); // NN
    float* ad_    = as_ + NN;                        // NN
    float* g      = ad_ + NN;                        // NN*64 f32 (ebuf aliases)
    float* pooled = g + (size_t)NN * HID;            // NG*64
    float* cntp   = pooled + NG * HID;               // NG
    int*   deg    = (int*)(cntp + NG);               // NN
    int*   cursor = deg + NN;                        // NN
    int*   csr    = cursor + NN;                     // NE
    int*   gcur   = csr + NE;                        // NBUCK
    int*   ebuf   = (int*)g;                         // NBUCK*KC_CAP (4.6MB < 12.8MB)

    k_xw<<<(NN + 63) / 64, 256, 0, stream>>>(x, W, att_s, att_d, hb, as_, ad_, gcur);

    k_bucket<<<(NE + CHUNK - 1) / CHUNK, 256, 0, stream>>>(src, dst, gcur, ebuf);
    k_csr<<<NBUCK, 256, 0, stream>>>(gcur, ebuf, csr, cursor, deg);

    k_gather<<<(NN + 3) / 4, 256, 0, stream>>>(csr, cursor, deg, hb, as_, ad_, bias, g, pooled);

    k_node<<<(NN / (4 * NPW)) + 1, 256, 0, stream>>>(g, batch, pooled, cntp);

    k_final<<<1, 256, 0, stream>>>(pooled, cntp, w1, b1, w2, b2, out);
}

// Round 12
// 133.336 us; speedup vs baseline: 1.0907x; 1.0701x over previous
//
#include <hip/hip_runtime.h>
#include <hip/hip_bf16.h>

#define NN 50000
#define NE 800000
#define NG 64
#define HID 64
#define NEG 0.2f
#define NPW 64          // nodes per wave in k_node
#define NBUCK 196       // ceil(NN/256) coarse buckets (dst>>8)
#define CHUNK 2048      // edges per k_bucket block
#define KC_CAP 6144     // per-bucket ebuf segment (mean 4096 + 32 sigma)

// bf16 <-> f32 helpers (RNE pack, exact unpack)
__device__ __forceinline__ unsigned short f2bf(float f) {
    unsigned int u = __float_as_uint(f);
    unsigned int r = (u + 0x7FFF + ((u >> 16) & 1)) >> 16;   // round-nearest-even
    return (unsigned short)r;
}
__device__ __forceinline__ float bf_lo(unsigned int p) {    // low bf16 of packed pair
    return __uint_as_float(p << 16);
}
__device__ __forceinline__ float bf_hi(unsigned int p) {    // high bf16
    return __uint_as_float(p & 0xFFFF0000u);
}

// ---------------- K1: h(bf16) = x @ W ; a_s ; a_d --------------------------
// Register-tiled f32 GEMM; h stored bf16. Block 0 zeroes gcur.
__global__ __launch_bounds__(256)
void k_xw(const float* __restrict__ x, const float* __restrict__ W,
          const float* __restrict__ att_s, const float* __restrict__ att_d,
          unsigned short* __restrict__ hb, float* __restrict__ as_, float* __restrict__ ad_,
          int* __restrict__ gcur) {
    __shared__ __align__(16) float sW[64][64];    // [k][c]
    __shared__ __align__(16) float sxT[64][68];   // [k][r]
    int t = threadIdx.x;
    if (blockIdx.x == 0 && t < NBUCK) gcur[t] = 0;
    int r0 = blockIdx.x * 64;
    for (int i = t; i < 4096; i += 256) sW[i >> 6][i & 63] = W[i];
    for (int i = t; i < 4096; i += 256) {
        int r = i >> 6, c = i & 63;
        int gr = r0 + r; if (gr >= NN) gr = NN - 1;
        sxT[c][r] = x[(size_t)gr * 64 + c];
    }
    __syncthreads();

    int tx = t & 15, ty = t >> 4;
    float4 asv = ((const float4*)att_s)[tx];
    float4 adv = ((const float4*)att_d)[tx];

    float acc[4][4] = {};
    #pragma unroll
    for (int k = 0; k < 64; ++k) {
        float4 a = *(const float4*)&sxT[k][4 * ty];
        float4 b = *(const float4*)&sW[k][4 * tx];
        float av[4] = {a.x, a.y, a.z, a.w};
        float bv[4] = {b.x, b.y, b.z, b.w};
        #pragma unroll
        for (int i = 0; i < 4; ++i)
            #pragma unroll
            for (int j = 0; j < 4; ++j)
                acc[i][j] += av[i] * bv[j];
    }

    #pragma unroll
    for (int i = 0; i < 4; ++i) {
        int r = r0 + 4 * ty + i;
        if (r < NN) {
            ushort4 hv;
            hv.x = f2bf(acc[i][0]); hv.y = f2bf(acc[i][1]);
            hv.z = f2bf(acc[i][2]); hv.w = f2bf(acc[i][3]);
            *(ushort4*)&hb[(size_t)r * 64 + 4 * tx] = hv;     // 8B store
            float ps = acc[i][0]*asv.x + acc[i][1]*asv.y + acc[i][2]*asv.z + acc[i][3]*asv.w;
            float pd = acc[i][0]*adv.x + acc[i][1]*adv.y + acc[i][2]*adv.z + acc[i][3]*adv.w;
            #pragma unroll
            for (int m = 1; m <= 8; m <<= 1) {
                ps += __shfl_xor(ps, m, 64);
                pd += __shfl_xor(pd, m, 64);
            }
            if (tx == 0) { as_[r] = ps; ad_[r] = pd; }
        }
    }
}

// ---------------- Pass B: blockwise bucket sort (dst>>8) ------------------
__global__ __launch_bounds__(256)
void k_bucket(const int* __restrict__ src, const int* __restrict__ dst,
              int* __restrict__ gcur, int* __restrict__ ebuf) {
    __shared__ int lhist[256], lscan[256], loff[256], lcur[256], gbase[256];
    __shared__ int lsort[CHUNK];
    __shared__ unsigned char lbuck[CHUNK];
    int t = threadIdx.x;
    int base = blockIdx.x * CHUNK;
    int cnt = NE - base; if (cnt > CHUNK) cnt = CHUNK; if (cnt < 0) cnt = 0;

    int ds[8], ss[8];
    int nv = 0;
    #pragma unroll
    for (int j = 0; j < 8; ++j) {
        int e = base + j * 256 + t;
        if (e < NE) { ds[nv] = dst[e]; ss[nv] = src[e]; ++nv; }
    }
    lhist[t] = 0;
    __syncthreads();
    for (int j = 0; j < nv; ++j) atomicAdd(&lhist[ds[j] >> 8], 1);
    __syncthreads();
    lscan[t] = lhist[t];
    __syncthreads();
    for (int off = 1; off < 256; off <<= 1) {
        int u = (t >= off) ? lscan[t - off] : 0;
        __syncthreads();
        lscan[t] += u;
        __syncthreads();
    }
    loff[t] = lscan[t] - lhist[t];   // exclusive
    lcur[t] = 0;
    __syncthreads();
    for (int j = 0; j < nv; ++j) {
        int b = ds[j] >> 8;
        int r = atomicAdd(&lcur[b], 1);
        int slot = loff[b] + r;
        lsort[slot] = (ss[j] << 8) | (ds[j] & 255);   // src<50000 fits in 24b
        lbuck[slot] = (unsigned char)b;
    }
    if (t < NBUCK) {
        int c = lhist[t];
        gbase[t] = c ? atomicAdd(&gcur[t], c) : 0;    // offset WITHIN bucket t
    }
    __syncthreads();
    for (int i = t; i < cnt; i += 256) {
        int b = lbuck[i];
        ebuf[b * KC_CAP + gbase[b] + (i - loff[b])] = lsort[i];
    }
}

// ---------------- Pass C: exact CSR within each bucket --------------------
__global__ __launch_bounds__(256)
void k_csr(const int* __restrict__ gcur, const int* __restrict__ ebuf,
           int* __restrict__ csr, int* __restrict__ cursor, int* __restrict__ deg) {
    __shared__ int lhist[256], lscan[256], loff[256], lcur[256], bscan[256];
    __shared__ int lsrc[KC_CAP];
    int t = threadIdx.x;
    int b = blockIdx.x;

    bscan[t] = (t < NBUCK) ? gcur[t] : 0;     // bucket sizes
    __syncthreads();
    for (int off = 1; off < 256; off <<= 1) {
        int u = (t >= off) ? bscan[t - off] : 0;
        __syncthreads();
        bscan[t] += u;
        __syncthreads();
    }
    int sz = gcur[b];                          // this bucket's edge count
    int gb = bscan[b] - sz;                    // dense CSR base (exclusive)
    const int* seg = ebuf + b * KC_CAP;

    lhist[t] = 0;
    __syncthreads();
    for (int i = t; i < sz; i += 256)
        atomicAdd(&lhist[seg[i] & 255], 1);
    __syncthreads();
    lscan[t] = lhist[t];
    __syncthreads();
    for (int off = 1; off < 256; off <<= 1) {
        int u = (t >= off) ? lscan[t - off] : 0;
        __syncthreads();
        lscan[t] += u;
        __syncthreads();
    }
    loff[t] = lscan[t] - lhist[t];
    lcur[t] = 0;
    __syncthreads();
    for (int i = t; i < sz; i += 256) {
        int w = seg[i];
        int dl = w & 255;
        int r = atomicAdd(&lcur[dl], 1);
        lsrc[loff[dl] + r] = w >> 8;
    }
    __syncthreads();
    for (int i = t; i < sz; i += 256)
        csr[gb + i] = lsrc[i];
    int d = b * 256 + t;
    if (d < NN) {
        deg[d] = lhist[t];
        cursor[d] = gb + loff[t] + lhist[t];   // end offset
    }
}

// ---------------- K2': gather, 8 edges per wave-iteration -----------------
// Wave = 8 groups x 8 lanes. Group g owns edge c0+g; lane cc=lane&7 owns
// channels 8cc..8cc+7. One uint4 load covers 8 rows' slices (1024B/wave).
// No shuffles in the loop; epilogue xor-reduce (8/16/32) over groups.
__global__ __launch_bounds__(256)
void k_gather(const int* __restrict__ csr, const int* __restrict__ cursor,
              const int* __restrict__ deg, const unsigned short* __restrict__ hb,
              const float* __restrict__ as_, const float* __restrict__ ad_,
              const float* __restrict__ bias, float* __restrict__ g,
              float* __restrict__ poolz) {
    int t = threadIdx.x;
    if (blockIdx.x == 0) {                        // replaces hipMemsetAsync
        for (int i = t; i < NG * HID + NG; i += 256) poolz[i] = 0.f;
    }
    int wave = t >> 6, lane = t & 63;
    int d = blockIdx.x * 4 + wave;
    if (d >= NN) return;
    int grp = lane >> 3;          // edge group 0..7
    int cc  = lane & 7;           // channel slice
    int cend = cursor[d];
    int nd   = deg[d];
    int cbeg = cend - nd;
    float adv = ad_[d];

    float acc[8] = {};
    float den = 0.f;

    // self-loop: weight nonzero only in group 0 (summed once by the reduce)
    {
        float e0 = as_[d] + adv;
        e0 = e0 >= 0.f ? e0 : NEG * e0;
        float ex0 = (grp == 0) ? __expf(e0) : 0.f;
        den += ex0;
        uint4 v = *(const uint4*)&hb[(size_t)d * 64 + 8 * cc];
        acc[0] += bf_lo(v.x) * ex0;  acc[1] += bf_hi(v.x) * ex0;
        acc[2] += bf_lo(v.y) * ex0;  acc[3] += bf_hi(v.y) * ex0;
        acc[4] += bf_lo(v.z) * ex0;  acc[5] += bf_hi(v.z) * ex0;
        acc[6] += bf_lo(v.w) * ex0;  acc[7] += bf_hi(v.w) * ex0;
    }

    for (int c0 = 0; c0 < nd; c0 += 8) {
        int  e  = c0 + grp;
        bool ok = e < nd;
        int  ci = cbeg + (ok ? e : (nd - 1));
        int    s = csr[ci];                       // 8 edges / 1 dword load
        float  a = as_[s];
        float av = a + adv;
        av = av >= 0.f ? av : NEG * av;
        float ex = ok ? __expf(av) : 0.f;
        den += ex;
        uint4 v = *(const uint4*)&hb[(size_t)s * 64 + 8 * cc];   // 16B/lane
        acc[0] += bf_lo(v.x) * ex;  acc[1] += bf_hi(v.x) * ex;
        acc[2] += bf_lo(v.y) * ex;  acc[3] += bf_hi(v.y) * ex;
        acc[4] += bf_lo(v.z) * ex;  acc[5] += bf_hi(v.z) * ex;
        acc[6] += bf_lo(v.w) * ex;  acc[7] += bf_hi(v.w) * ex;
    }

    // reduce across the 8 groups (lanes with same cc)
    #pragma unroll
    for (int m = 8; m <= 32; m <<= 1) {
        den += __shfl_xor(den, m, 64);
        #pragma unroll
        for (int k = 0; k < 8; ++k) acc[k] += __shfl_xor(acc[k], m, 64);
    }

    if (grp == 0) {                               // 8 lanes write the row
        float inv = 1.f / den;
        float4 b0 = ((const float4*)bias)[2 * cc];
        float4 b1 = ((const float4*)bias)[2 * cc + 1];
        float4 o0, o1;
        o0.x = fmaxf(acc[0] * inv + b0.x, 0.f);
        o0.y = fmaxf(acc[1] * inv + b0.y, 0.f);
        o0.z = fmaxf(acc[2] * inv + b0.z, 0.f);
        o0.w = fmaxf(acc[3] * inv + b0.w, 0.f);
        o1.x = fmaxf(acc[4] * inv + b1.x, 0.f);
        o1.y = fmaxf(acc[5] * inv + b1.y, 0.f);
        o1.z = fmaxf(acc[6] * inv + b1.z, 0.f);
        o1.w = fmaxf(acc[7] * inv + b1.w, 0.f);
        *(float4*)&g[(size_t)d * 64 + 8 * cc]     = o0;
        *(float4*)&g[(size_t)d * 64 + 8 * cc + 4] = o1;
    }
}

// ---------------- K3: pooled partial sums (batch sorted, run-length) ------
__global__ __launch_bounds__(256)
void k_node(const float* __restrict__ g, const int* __restrict__ batch,
            float* __restrict__ pooled, float* __restrict__ cnt) {
    int t = threadIdx.x;
    int wave = t >> 6, lane = t & 63;
    int n0 = (blockIdx.x * 4 + wave) * NPW;
    if (n0 >= NN) return;
    int n1 = n0 + NPW; if (n1 > NN) n1 = NN;
    float acc = 0.f, c = 0.f;
    int cur = batch[n0];
    for (int n = n0; n < n1; ++n) {
        int gr = batch[n];
        if (gr != cur) {
            atomicAdd(&pooled[cur * 64 + lane], acc);
            if (lane == 0) atomicAdd(&cnt[cur], c);
            acc = 0.f; c = 0.f; cur = gr;
        }
        acc += g[(size_t)n * 64 + lane];
        c += 1.f;
    }
    atomicAdd(&pooled[cur * 64 + lane], acc);
    if (lane == 0) atomicAdd(&cnt[cur], c);
}

// ---------------- K4: mean + MLP + sigmoid (single block) ------------------
__global__ __launch_bounds__(256)
void k_final(const float* __restrict__ pooled, const float* __restrict__ cnt,
             const float* __restrict__ w1, const float* __restrict__ b1,
             const float* __restrict__ w2, const float* __restrict__ b2,
             float* __restrict__ out) {
    __shared__ float sp[64][65];
    __shared__ float sz[64][65];
    int t = threadIdx.x;
    for (int i = t; i < 4096; i += 256) {
        int g = i >> 6, c = i & 63;
        sp[g][c] = pooled[i] / fmaxf(cnt[g], 1.0f);
    }
    __syncthreads();
    for (int i = t; i < 4096; i += 256) {
        int g = i >> 6, c = i & 63;
        float acc = b1[c];
        #pragma unroll
        for (int k = 0; k < 64; ++k) acc += sp[g][k] * w1[k * 64 + c];
        sz[g][c] = fmaxf(acc, 0.f);
    }
    __syncthreads();
    if (t < 64) {
        float acc = b2[0];
        #pragma unroll
        for (int c = 0; c < 64; ++c) acc += sz[t][c] * w2[c];
        out[t] = 1.f / (1.f + __expf(-acc));
    }
}

extern "C" void kernel_launch(void* const* d_in, const int* in_sizes, int n_in,
                              void* d_out, int out_size, void* d_ws, size_t ws_size,
                              hipStream_t stream) {
    const float* x     = (const float*)d_in[0];
    const int*   ei    = (const int*)d_in[1];   // [2, NE] flat: src row then dst row
    const int*   batch = (const int*)d_in[2];
    const float* W     = (const float*)d_in[3];
    const float* att_s = (const float*)d_in[4];
    const float* att_d = (const float*)d_in[5];
    const float* bias  = (const float*)d_in[6];
    const float* w1    = (const float*)d_in[7];
    const float* b1    = (const float*)d_in[8];
    const float* w2    = (const float*)d_in[9];
    const float* b2    = (const float*)d_in[10];
    float* out = (float*)d_out;

    const int* src = ei;
    const int* dst = ei + NE;

    // workspace layout
    unsigned short* hb = (unsigned short*)d_ws;      // NN*64 bf16
    float* as_    = (float*)(hb + (size_t)NN * HID); // NN
    float* ad_    = as_ + NN;                        // NN
    float* g      = ad_ + NN;                        // NN*64 f32 (ebuf aliases)
    float* pooled = g + (size_t)NN * HID;            // NG*64
    float* cntp   = pooled + NG * HID;               // NG
    int*   deg    = (int*)(cntp + NG);               // NN
    int*   cursor = deg + NN;                        // NN
    int*   csr    = cursor + NN;                     // NE
    int*   gcur   = csr + NE;                        // NBUCK
    int*   ebuf   = (int*)g;                         // NBUCK*KC_CAP (4.6MB < 12.8MB)

    k_xw<<<(NN + 63) / 64, 256, 0, stream>>>(x, W, att_s, att_d, hb, as_, ad_, gcur);

    k_bucket<<<(NE + CHUNK - 1) / CHUNK, 256, 0, stream>>>(src, dst, gcur, ebuf);
    k_csr<<<NBUCK, 256, 0, stream>>>(gcur, ebuf, csr, cursor, deg);

    k_gather<<<(NN + 3) / 4, 256, 0, stream>>>(csr, cursor, deg, hb, as_, ad_, bias, g, pooled);

    k_node<<<(NN / (4 * NPW)) + 1, 256, 0, stream>>>(g, batch, pooled, cntp);

    k_final<<<1, 256, 0, stream>>>(pooled, cntp, w1, b1, w2, b2, out);
}